// Round 2
// baseline (640.813 us; speedup 1.0000x reference)
//
#include <hip/hip_runtime.h>
#include <cstdint>
#include <cstddef>

#define NFEAT 128
#define KBUCK 1024
#define NPW 4   // nodes per wave in spmm

typedef __attribute__((ext_vector_type(8))) short bf16x8;
typedef __attribute__((ext_vector_type(4))) float f32x4;

// bf16 <-> f32 helpers (RNE, no NaN handling needed — activations are finite)
__device__ __forceinline__ unsigned short f2bf(float x) {
    union { float f; unsigned u; } v; v.f = x;
    unsigned r = v.u + 0x7fffu + ((v.u >> 16) & 1u);
    return (unsigned short)(r >> 16);
}
__device__ __forceinline__ float bf2f(unsigned short b) {
    union { unsigned u; float f; } v; v.u = ((unsigned)b) << 16;
    return v.f;
}
__device__ __forceinline__ float u2f(unsigned u) {
    union { unsigned u; float f; } v; v.u = u; return v.f;
}

// ---------------- preprocessing kernels ----------------

__global__ void zero_ints(int* __restrict__ p, int n) {
    int i = blockIdx.x * blockDim.x + threadIdx.x;
    if (i < n) p[i] = 0;
}

__global__ void cast_bf16_kernel(const float* __restrict__ x, unsigned short* __restrict__ y, int n4) {
    int i = blockIdx.x * blockDim.x + threadIdx.x;
    if (i < n4) {
        float4 v = ((const float4*)x)[i];
        ushort4 o;
        o.x = f2bf(v.x); o.y = f2bf(v.y); o.z = f2bf(v.z); o.w = f2bf(v.w);
        ((ushort4*)y)[i] = o;
    }
}

// Pack Wcat (256 x NCOL: rows 0..127 = gcW, 128..255 = resW; fp32) into bf16 MFMA
// B-fragment order for K=256 GEMM:
// Wf[((kb*NT + nt)*64 + lane)*8 + j] = Wcat[kb*32 + (lane>>4)*8 + j][nt*16 + (lane&15)]
template <int NCOL>
__global__ void prep_wf2(const float* __restrict__ gcW, const float* __restrict__ resW,
                         unsigned short* __restrict__ Wf) {
    constexpr int NT = NCOL / 16;
    int tid = blockIdx.x * 256 + threadIdx.x;
    if (tid >= 256 * NCOL) return;
    int k = tid / NCOL, c = tid % NCOL;
    float v = (k < 128) ? gcW[k * NCOL + c] : resW[(k - 128) * NCOL + c];
    int kb = k >> 5, koff = k & 31, quad = koff >> 3, j = koff & 7;
    int nt = c >> 4, ncol = c & 15, lane = quad * 16 + ncol;
    Wf[((kb * NT + nt) * 64 + lane) * 8 + j] = f2bf(v);
}

// ---------------- fully-bucketed graph preprocessing ----------------

__global__ __launch_bounds__(256) void hist_kernel(
    const int* __restrict__ src, const int* __restrict__ dst, int ne, int D,
    int* __restrict__ dst_btot, int* __restrict__ src_btot) {
    __shared__ int hd[KBUCK], hs[KBUCK];
    const int t = threadIdx.x;
    const int tile0 = blockIdx.x * 4096;
    for (int i = t; i < KBUCK; i += 256) { hd[i] = 0; hs[i] = 0; }
    __syncthreads();
    #pragma unroll
    for (int j = 0; j < 16; j++) {
        int e = tile0 + j * 256 + t;
        if (e < ne) {
            atomicAdd(&hd[(unsigned)dst[e] / (unsigned)D], 1);
            atomicAdd(&hs[(unsigned)src[e] / (unsigned)D], 1);
        }
    }
    __syncthreads();
    for (int i = t; i < KBUCK; i += 256) {
        if (hd[i]) atomicAdd(&dst_btot[i], hd[i]);
        if (hs[i]) atomicAdd(&src_btot[i], hs[i]);
    }
}

__global__ __launch_bounds__(KBUCK) void scan_buckets(
    const int* __restrict__ dst_btot, const int* __restrict__ src_btot,
    int* __restrict__ dst_base, int* __restrict__ src_base,
    int* __restrict__ dst_cursor, int* __restrict__ src_cursor,
    int* __restrict__ row_ptr, int n, int ne) {
    __shared__ int t1[KBUCK], t2[KBUCK];
    const int t = threadIdx.x;
    int v1 = dst_btot[t], v2 = src_btot[t];
    t1[t] = v1; t2[t] = v2;
    for (int off = 1; off < KBUCK; off <<= 1) {
        __syncthreads();
        int a = (t >= off) ? t1[t - off] : 0;
        int b = (t >= off) ? t2[t - off] : 0;
        __syncthreads();
        t1[t] += a; t2[t] += b;
    }
    __syncthreads();
    int e1 = t1[t] - v1, e2 = t2[t] - v2;
    dst_base[t] = e1; src_base[t] = e2;
    dst_cursor[t] = e1; src_cursor[t] = e2;
    if (t == KBUCK - 1) {
        dst_base[KBUCK] = t1[t];
        src_base[KBUCK] = t2[t];
        row_ptr[n] = ne;
    }
}

__global__ __launch_bounds__(256) void partition_dst(
    const int* __restrict__ src, const int* __restrict__ dst, int ne, int D,
    int* __restrict__ dst_cursor, uint2* __restrict__ ebuf) {
    __shared__ int hist[KBUCK];
    __shared__ int gbase[KBUCK];
    const int t = threadIdx.x;
    const int tile0 = blockIdx.x * 4096;

    for (int i = t; i < KBUCK; i += 256) hist[i] = 0;
    __syncthreads();

    int s[16], d[16], r[16];
    #pragma unroll
    for (int j = 0; j < 16; j++) {
        int e = tile0 + j * 256 + t;
        if (e < ne) {
            s[j] = src[e];
            d[j] = dst[e];
            int b = (int)((unsigned)d[j] / (unsigned)D);
            r[j] = atomicAdd(&hist[b], 1);
        }
    }
    __syncthreads();
    for (int i = t; i < KBUCK; i += 256) {
        int c = hist[i];
        gbase[i] = c ? atomicAdd(&dst_cursor[i], c) : 0;
    }
    __syncthreads();
    #pragma unroll
    for (int j = 0; j < 16; j++) {
        int e = tile0 + j * 256 + t;
        if (e < ne) {
            int b = (int)((unsigned)d[j] / (unsigned)D);
            ebuf[gbase[b] + r[j]] = make_uint2((unsigned)s[j], (unsigned)d[j]);
        }
    }
}

__global__ __launch_bounds__(256) void partition_src(
    const int* __restrict__ src, int ne, int D,
    int* __restrict__ src_cursor, unsigned* __restrict__ sbuf) {
    __shared__ int hist[KBUCK];
    __shared__ int gbase[KBUCK];
    const int t = threadIdx.x;
    const int tile0 = blockIdx.x * 4096;

    for (int i = t; i < KBUCK; i += 256) hist[i] = 0;
    __syncthreads();

    int s[16], r[16];
    #pragma unroll
    for (int j = 0; j < 16; j++) {
        int e = tile0 + j * 256 + t;
        if (e < ne) {
            s[j] = src[e];
            int b = (int)((unsigned)s[j] / (unsigned)D);
            r[j] = atomicAdd(&hist[b], 1);
        }
    }
    __syncthreads();
    for (int i = t; i < KBUCK; i += 256) {
        int c = hist[i];
        gbase[i] = c ? atomicAdd(&src_cursor[i], c) : 0;
    }
    __syncthreads();
    #pragma unroll
    for (int j = 0; j < 16; j++) {
        int e = tile0 + j * 256 + t;
        if (e < ne) {
            int b = (int)((unsigned)s[j] / (unsigned)D);
            sbuf[gbase[b] + r[j]] = (unsigned)s[j];
        }
    }
}

// build_dst emits fused CSR entries {src, norm_s[src]} (uint2): one level of random
// indirection in spmm. norm_s built first (build_src launched before build_dst).
__global__ __launch_bounds__(256) void build_dst(
    const uint2* __restrict__ ebuf, const int* __restrict__ dst_base,
    const float* __restrict__ norm_s,
    int n, int D, int* __restrict__ row_ptr, float* __restrict__ norm_d,
    uint2* __restrict__ csr_e) {
    __shared__ int cnt[128], sc[128], rp[128], rank[128];
    const int b = blockIdx.x;
    const int d_lo = b * D;
    if (d_lo >= n) return;
    const int d_hi = (d_lo + D < n) ? d_lo + D : n;
    const int e0 = dst_base[b], e1 = dst_base[b + 1];
    const int t = threadIdx.x;

    if (t < 128) { cnt[t] = 0; rank[t] = 0; }
    __syncthreads();
    for (int i = e0 + t; i < e1; i += 256)
        atomicAdd(&cnt[(int)ebuf[i].y - d_lo], 1);
    __syncthreads();
    if (t < 128) sc[t] = cnt[t];
    __syncthreads();
    for (int off = 1; off < 128; off <<= 1) {
        int v = (t < 128 && t >= off) ? sc[t - off] : 0;
        __syncthreads();
        if (t < 128) sc[t] += v;
        __syncthreads();
    }
    if (t < 128) {
        rp[t] = e0 + sc[t] - cnt[t];   // exclusive
        int d = d_lo + t;
        if (d < d_hi) {
            row_ptr[d] = rp[t];
            norm_d[d] = rsqrtf(fmaxf((float)cnt[t], 1.0f));
        }
    }
    __syncthreads();
    for (int i = e0 + t; i < e1; i += 256) {
        uint2 ed = ebuf[i];
        int dd = (int)ed.y - d_lo;
        int r = atomicAdd(&rank[dd], 1);
        csr_e[rp[dd] + r] = make_uint2(ed.x, __float_as_uint(norm_s[(int)ed.x]));
    }
}

__global__ __launch_bounds__(256) void build_src(
    const unsigned* __restrict__ sbuf, const int* __restrict__ src_base,
    int n, int D, float* __restrict__ norm_s) {
    __shared__ int cnt[128];
    const int b = blockIdx.x;
    const int d_lo = b * D;
    if (d_lo >= n) return;
    const int d_hi = (d_lo + D < n) ? d_lo + D : n;
    const int e0 = src_base[b], e1 = src_base[b + 1];
    const int t = threadIdx.x;
    if (t < 128) cnt[t] = 0;
    __syncthreads();
    for (int i = e0 + t; i < e1; i += 256)
        atomicAdd(&cnt[(int)sbuf[i] - d_lo], 1);
    __syncthreads();
    if (t < 128 && d_lo + t < d_hi)
        norm_s[d_lo + t] = rsqrtf(fmaxf((float)cnt[t], 1.0f));
}

// ---------------- aggregate-first SpMM: U = [norm_d .* (A@(norm_s.*x)) | A@x] ----------------
// Round-10: CROSS-NODE 3-stage software pipeline. Avg degree = 16 = one chunk, so
// within-row pipelining has no steady state (round-9 lesson). Each wave owns NPW=4
// consecutive nodes whose CSR ranges are contiguous; a scalar state machine walks the
// chunk stream and the pipeline runs: ENTRY(chunk t+2: broadcast entry loads ->
// readfirstlane -> SGPR) || GATHER(chunk t+1: 16 scalar-base row loads) ||
// COMPUTE(chunk t). Invalid/pad edges are redirected at ENTRY to a zeroed row X[n]
// (scalar cselect) so the inner compute has ZERO masking VALU: 2 shifts + 2 adds +
// 2 fmas per edge. csr_e has 48 zeroed slack entries; X has a zeroed row n.

__global__ __launch_bounds__(256) void spmm_pre(
    const unsigned short* __restrict__ X, const int* __restrict__ row_ptr,
    const uint2* __restrict__ csr_e, const float* __restrict__ norm_d,
    unsigned short* __restrict__ U, int n) {
    const int wid = (blockIdx.x * 256 + threadIdx.x) >> 6;
    const int lane = threadIdx.x & 63;
    const int base = wid * NPW;
    if (base >= n) return;

    // row boundaries (contiguous across the NPW nodes) + norm_d, prefetched scalar
    int r0 = __builtin_amdgcn_readfirstlane(row_ptr[base]);
    int r1 = __builtin_amdgcn_readfirstlane(row_ptr[base + 1]);
    int r2 = __builtin_amdgcn_readfirstlane(row_ptr[base + 2]);
    int r3 = __builtin_amdgcn_readfirstlane(row_ptr[base + 3]);
    int r4 = __builtin_amdgcn_readfirstlane(row_ptr[base + 4]);
    float nd0 = norm_d[base], nd1 = norm_d[base + 1];
    float nd2 = norm_d[base + 2], nd3 = norm_d[base + 3];

    // total chunks m = sum over nodes of max(1, ceil(deg/16))
    int m = 0;
    {
        int d0 = r1 - r0, d1 = r2 - r1, d2 = r3 - r2, d3 = r4 - r3;
        m += (d0 <= 16) ? 1 : ((d0 + 15) >> 4);
        m += (d1 <= 16) ? 1 : ((d1 + 15) >> 4);
        m += (d2 <= 16) ? 1 : ((d2 + 15) >> 4);
        m += (d3 <= 16) ? 1 : ((d3 + 15) >> 4);
    }

    // front state (scalar): current chunk start cF, its node-end e1F, node index kF,
    // and the upcoming boundaries (shift registers; sentinel = r4)
    int cF = r0, e1F = r1, kF = 0;
    int nb1 = r2, nb2 = r3, nb3 = r4;

    // pipeline slots
    int   s0[16], s1[16], s2[16];
    float w0[16], w1[16], w2[16];
    unsigned q0[16], q1[16], q2[16];
    int last0 = 0, last1 = 0, last2 = 0;
    int k0 = 0, k1 = 0, k2 = 0;

    // accumulators: lane holds cols [2*lane, 2*lane+1]
    float ap0 = 0.f, ap1 = 0.f, as0 = 0.f, as1 = 0.f;

#define ENTRY(S, W, LAST, KS)                                                   \
    {                                                                           \
        LAST = (cF + 16 >= e1F) ? 1 : 0;                                        \
        KS = kF;                                                                \
        const uint2* ep = csr_e + cF;                                           \
        _Pragma("unroll")                                                       \
        for (int i = 0; i < 16; i++) {                                          \
            uint2 E = ep[i];                                                    \
            int sv = __builtin_amdgcn_readfirstlane((int)E.x);                  \
            int wv = __builtin_amdgcn_readfirstlane((int)E.y);                  \
            int val = (cF + i) < e1F;                                           \
            S[i] = val ? sv : n;                                                \
            W[i] = u2f(val ? (unsigned)wv : 0u);                                \
        }                                                                       \
        int cn = cF + 16;                                                       \
        if (cn >= e1F) { cF = e1F; kF++; e1F = nb1; nb1 = nb2; nb2 = nb3; }     \
        else cF = cn;                                                           \
    }

#define GATHER(S, Q)                                                            \
    {                                                                           \
        _Pragma("unroll")                                                       \
        for (int i = 0; i < 16; i++) {                                          \
            const unsigned short* rb = X + (size_t)(unsigned)S[i] * NFEAT;      \
            Q[i] = *(const unsigned*)(rb + (lane << 1));                        \
        }                                                                       \
    }

#define COMPUTE(Q, W, LAST, KS)                                                 \
    {                                                                           \
        _Pragma("unroll")                                                       \
        for (int i = 0; i < 16; i++) {                                          \
            unsigned qq = Q[i];                                                 \
            float x0 = u2f(qq << 16);                                           \
            float x1 = u2f(qq & 0xffff0000u);                                   \
            ap0 += x0; ap1 += x1;                                               \
            as0 = fmaf(W[i], x0, as0);                                          \
            as1 = fmaf(W[i], x1, as1);                                          \
        }                                                                       \
        if (LAST && KS < NPW) {                                                 \
            float nd = (KS == 0) ? nd0 : (KS == 1) ? nd1 : (KS == 2) ? nd2 : nd3; \
            unsigned short* Ur = U + (size_t)(base + KS) * 256;                 \
            ushort2 gcv, rsv;                                                   \
            gcv.x = f2bf(nd * as0); gcv.y = f2bf(nd * as1);                     \
            rsv.x = f2bf(ap0);      rsv.y = f2bf(ap1);                          \
            *(ushort2*)(Ur + lane * 2) = gcv;                                   \
            *(ushort2*)(Ur + 128 + lane * 2) = rsv;                             \
            ap0 = 0.f; ap1 = 0.f; as0 = 0.f; as1 = 0.f;                         \
        }                                                                       \
    }

    // prologue: fill two stages
    ENTRY(s0, w0, last0, k0);
    ENTRY(s1, w1, last1, k1);
    GATHER(s0, q0);

    // main loop: 3-phase rotation; overrun (<=2 chunks) is harmless — dummy chunks
    // have e1==c (all edges redirected to the zero row, weight 0, no finalize).
    for (int done = 0; done < m; done += 3) {
        ENTRY(s2, w2, last2, k2); GATHER(s1, q1); COMPUTE(q0, w0, last0, k0);
        ENTRY(s0, w0, last0, k0); GATHER(s2, q2); COMPUTE(q1, w1, last1, k1);
        ENTRY(s1, w1, last1, k1); GATHER(s0, q0); COMPUTE(q2, w2, last2, k2);
    }
#undef ENTRY
#undef GATHER
#undef COMPUTE
}

// ---------------- MFMA GEMM: y = U @ [W;R] + b (+relu), K=256 ----------------
// U: [M,256] bf16. Wf: fragment-major bf16 (prep_wf2). Block = 4 waves; wave w does
// rows blockIdx.x*64 + w*16, all NCOL cols. A (16x256) = 8 bf16x8 frags in registers.
// mfma_f32_16x16x32_bf16 layouts (HW-verified m89/m91): A[m=lane&15][k=(lane>>4)*8+j],
// C/D col=lane&15, row=(lane>>4)*4+reg.

template <int NCOL, bool RELU, bool OUT_BF16>
__global__ __launch_bounds__(256) void gemm_mfma(
    const unsigned short* __restrict__ U, int M,
    const unsigned short* __restrict__ Wf,
    const float* __restrict__ bias, void* __restrict__ outv) {
    constexpr int NT = NCOL / 16;
    __shared__ unsigned short Bs[256 * NCOL];

    const int t = threadIdx.x;
    const int wave = t >> 6, lane = t & 63;
    const int r0 = blockIdx.x * 64 + wave * 16;

    // stage Wf -> LDS (contiguous 16B copies, conflict-free)
    constexpr int TOT16 = 256 * NCOL * 2 / 16;
    const uint4* gsrc = (const uint4*)Wf;
    uint4* ldst = (uint4*)Bs;
    for (int i = t; i < TOT16; i += 256) ldst[i] = gsrc[i];

    // A fragments (rows am = r0 + (lane&15), k = kb*32 + (lane>>4)*8 + j)
    const int am = r0 + (lane & 15);
    const int kq = (lane >> 4) * 8;
    bf16x8 afrag[8];
    if (am < M) {
        const unsigned short* ap = U + (size_t)am * 256 + kq;
        #pragma unroll
        for (int kb = 0; kb < 8; kb++)
            afrag[kb] = *(const bf16x8*)(ap + kb * 32);
    } else {
        #pragma unroll
        for (int kb = 0; kb < 8; kb++) afrag[kb] = bf16x8{};
    }

    const int orow = r0 + (lane >> 4) * 4;
    __syncthreads();

    #pragma unroll 1
    for (int nt = 0; nt < NT; nt++) {
        f32x4 acc = {0.f, 0.f, 0.f, 0.f};
        #pragma unroll
        for (int kb = 0; kb < 8; kb++) {
            bf16x8 b = *(const bf16x8*)(Bs + ((kb * NT + nt) * 64 + lane) * 8);
            acc = __builtin_amdgcn_mfma_f32_16x16x32_bf16(afrag[kb], b, acc, 0, 0, 0);
        }
        const int gcol = nt * 16 + (lane & 15);
        const float bv = bias[gcol];
        #pragma unroll
        for (int r = 0; r < 4; r++) {
            int gm = orow + r;
            if (gm < M) {
                float v = acc[r] + bv;
                if (RELU) v = fmaxf(v, 0.f);
                if constexpr (OUT_BF16)
                    ((unsigned short*)outv)[(size_t)gm * NCOL + gcol] = f2bf(v);
                else
                    ((float*)outv)[(size_t)gm * NCOL + gcol] = v;
            }
        }
    }
}

// ---------------- launch ----------------

extern "C" void kernel_launch(void* const* d_in, const int* in_sizes, int n_in,
                              void* d_out, int out_size, void* d_ws, size_t ws_size,
                              hipStream_t stream) {
    const float* raw_x  = (const float*)d_in[0];
    const int*   src    = (const int*)d_in[1];
    const int*   dst    = (const int*)d_in[2];
    const float* gc_w0  = (const float*)d_in[3];
    const float* gc_b0  = (const float*)d_in[4];
    const float* gc_w1  = (const float*)d_in[5];
    const float* gc_b1  = (const float*)d_in[6];
    const float* gc_w2  = (const float*)d_in[7];
    const float* gc_b2  = (const float*)d_in[8];
    const float* res_w0 = (const float*)d_in[9];
    const float* res_w1 = (const float*)d_in[10];
    const float* res_w2 = (const float*)d_in[11];

    const int n  = in_sizes[0] / NFEAT;   // 100000
    const int ne = in_sizes[1];           // 1600000
    float* out = (float*)d_out;
    const int D = (n + KBUCK - 1) / KBUCK;   // nodes per bucket (98, <=128)

    // workspace layout (Xb/X1b have an extra zeroed row n; csr_e has 48 slack entries)
    char* w = (char*)d_ws;
    unsigned short* U   = (unsigned short*)w; w += (size_t)n * 256 * sizeof(unsigned short);       // 51.2 MB
    unsigned short* Xb  = (unsigned short*)w; w += (size_t)(n + 1) * 128 * sizeof(unsigned short); // 25.6 MB
    unsigned short* X1b = (unsigned short*)w; w += (size_t)(n + 1) * 128 * sizeof(unsigned short); // 25.6 MB
    float* norm_s = (float*)w;   w += (size_t)n * sizeof(float);
    float* norm_d = (float*)w;   w += (size_t)n * sizeof(float);
    int* row_ptr = (int*)w;      w += (size_t)(n + 1) * sizeof(int);
    uint2* csr_e = (uint2*)w;    w += (size_t)(ne + 48) * sizeof(uint2);   // 12.8 MB {src, ns}
    uint2* ebuf = (uint2*)w;     w += (size_t)ne * sizeof(uint2);          // 12.8 MB
    unsigned* sbuf = (unsigned*)w; w += (size_t)ne * sizeof(unsigned);     // 6.4 MB
    int* dst_btot = (int*)w;     w += KBUCK * sizeof(int);
    int* src_btot = (int*)w;     w += KBUCK * sizeof(int);
    int* dst_base = (int*)w;     w += (KBUCK + 1) * sizeof(int);
    int* src_base = (int*)w;     w += (KBUCK + 1) * sizeof(int);
    int* dst_cursor = (int*)w;   w += KBUCK * sizeof(int);
    int* src_cursor = (int*)w;   w += KBUCK * sizeof(int);
    unsigned short* Wf0 = (unsigned short*)w; w += 256 * 128 * sizeof(unsigned short);
    unsigned short* Wf1 = (unsigned short*)w; w += 256 * 128 * sizeof(unsigned short);
    unsigned short* Wf2 = (unsigned short*)w; w += 256 * 64 * sizeof(unsigned short);

    const int tiles = (ne + 4095) / 4096;

    // --- preprocessing: bf16 cast, weight fragments, bucketed CSR + degrees ---
    cast_bf16_kernel<<<(n * (NFEAT / 4) + 255) / 256, 256, 0, stream>>>(raw_x, Xb, n * (NFEAT / 4));
    // zero row n of Xb and X1b (spmm pad-redirect target), and csr_e slack entries
    zero_ints<<<1, 64, 0, stream>>>((int*)(Xb + (size_t)n * 128), 64);
    zero_ints<<<1, 64, 0, stream>>>((int*)(X1b + (size_t)n * 128), 64);
    zero_ints<<<1, 96, 0, stream>>>((int*)(csr_e + ne), 96);
    prep_wf2<128><<<128, 256, 0, stream>>>(gc_w0, res_w0, Wf0);
    prep_wf2<128><<<128, 256, 0, stream>>>(gc_w1, res_w1, Wf1);
    prep_wf2<64><<<64, 256, 0, stream>>>(gc_w2, res_w2, Wf2);
    zero_ints<<<(2 * KBUCK + 255) / 256, 256, 0, stream>>>(dst_btot, 2 * KBUCK); // dst_btot+src_btot contiguous
    hist_kernel<<<tiles, 256, 0, stream>>>(src, dst, ne, D, dst_btot, src_btot);
    scan_buckets<<<1, KBUCK, 0, stream>>>(dst_btot, src_btot, dst_base, src_base,
                                          dst_cursor, src_cursor, row_ptr, n, ne);
    partition_dst<<<tiles, 256, 0, stream>>>(src, dst, ne, D, dst_cursor, ebuf);
    partition_src<<<tiles, 256, 0, stream>>>(src, ne, D, src_cursor, sbuf);
    build_src<<<KBUCK, 256, 0, stream>>>(sbuf, src_base, n, D, norm_s);
    build_dst<<<KBUCK, 256, 0, stream>>>(ebuf, dst_base, norm_s, n, D, row_ptr, norm_d, csr_e);

    const int gemm_blocks = (n + 63) / 64;
    const int nwaves = (n + NPW - 1) / NPW;
    const int spmm_blocks = (nwaves * 64 + 255) / 256;

    // --- layer 0: x1 = relu([nd*A(ns*x) | A x] @ [W0;R0] + b0) ---
    spmm_pre<<<spmm_blocks, 256, 0, stream>>>(Xb, row_ptr, csr_e, norm_d, U, n);
    gemm_mfma<128, true, true><<<gemm_blocks, 256, 0, stream>>>(U, n, Wf0, gc_b0, X1b);

    // --- layer 1 ---
    spmm_pre<<<spmm_blocks, 256, 0, stream>>>(X1b, row_ptr, csr_e, norm_d, U, n);
    gemm_mfma<128, true, true><<<gemm_blocks, 256, 0, stream>>>(U, n, Wf1, gc_b1, X1b);

    // --- layer 2: output 64-wide fp32, no relu ---
    spmm_pre<<<spmm_blocks, 256, 0, stream>>>(X1b, row_ptr, csr_e, norm_d, U, n);
    gemm_mfma<64, false, false><<<gemm_blocks, 256, 0, stream>>>(U, n, Wf2, gc_b2, out);
}

// Round 3
// 522.118 us; speedup vs baseline: 1.2273x; 1.2273x over previous
//
#include <hip/hip_runtime.h>
#include <cstdint>
#include <cstddef>

#define NFEAT 128
#define KBUCK 1024

typedef __attribute__((ext_vector_type(8))) short bf16x8;
typedef __attribute__((ext_vector_type(4))) float f32x4;

// bf16 <-> f32 helpers (RNE, no NaN handling needed — activations are finite)
__device__ __forceinline__ unsigned short f2bf(float x) {
    union { float f; unsigned u; } v; v.f = x;
    unsigned r = v.u + 0x7fffu + ((v.u >> 16) & 1u);
    return (unsigned short)(r >> 16);
}
__device__ __forceinline__ float bf2f(unsigned short b) {
    union { unsigned u; float f; } v; v.u = ((unsigned)b) << 16;
    return v.f;
}
__device__ __forceinline__ float u2f(unsigned u) {
    union { unsigned u; float f; } v; v.u = u; return v.f;
}

// ---------------- preprocessing kernels ----------------

__global__ void zero_ints(int* __restrict__ p, int n) {
    int i = blockIdx.x * blockDim.x + threadIdx.x;
    if (i < n) p[i] = 0;
}

__global__ void cast_bf16_kernel(const float* __restrict__ x, unsigned short* __restrict__ y, int n4) {
    int i = blockIdx.x * blockDim.x + threadIdx.x;
    if (i < n4) {
        float4 v = ((const float4*)x)[i];
        ushort4 o;
        o.x = f2bf(v.x); o.y = f2bf(v.y); o.z = f2bf(v.z); o.w = f2bf(v.w);
        ((ushort4*)y)[i] = o;
    }
}

// Pack Wcat (256 x NCOL: rows 0..127 = gcW, 128..255 = resW; fp32) into bf16 MFMA
// B-fragment order for K=256 GEMM:
// Wf[((kb*NT + nt)*64 + lane)*8 + j] = Wcat[kb*32 + (lane>>4)*8 + j][nt*16 + (lane&15)]
template <int NCOL>
__global__ void prep_wf2(const float* __restrict__ gcW, const float* __restrict__ resW,
                         unsigned short* __restrict__ Wf) {
    constexpr int NT = NCOL / 16;
    int tid = blockIdx.x * 256 + threadIdx.x;
    if (tid >= 256 * NCOL) return;
    int k = tid / NCOL, c = tid % NCOL;
    float v = (k < 128) ? gcW[k * NCOL + c] : resW[(k - 128) * NCOL + c];
    int kb = k >> 5, koff = k & 31, quad = koff >> 3, j = koff & 7;
    int nt = c >> 4, ncol = c & 15, lane = quad * 16 + ncol;
    Wf[((kb * NT + nt) * 64 + lane) * 8 + j] = f2bf(v);
}

// ---------------- fully-bucketed graph preprocessing ----------------

__global__ __launch_bounds__(256) void hist_kernel(
    const int* __restrict__ src, const int* __restrict__ dst, int ne, int D,
    int* __restrict__ dst_btot, int* __restrict__ src_btot) {
    __shared__ int hd[KBUCK], hs[KBUCK];
    const int t = threadIdx.x;
    const int tile0 = blockIdx.x * 4096;
    for (int i = t; i < KBUCK; i += 256) { hd[i] = 0; hs[i] = 0; }
    __syncthreads();
    #pragma unroll
    for (int j = 0; j < 16; j++) {
        int e = tile0 + j * 256 + t;
        if (e < ne) {
            atomicAdd(&hd[(unsigned)dst[e] / (unsigned)D], 1);
            atomicAdd(&hs[(unsigned)src[e] / (unsigned)D], 1);
        }
    }
    __syncthreads();
    for (int i = t; i < KBUCK; i += 256) {
        if (hd[i]) atomicAdd(&dst_btot[i], hd[i]);
        if (hs[i]) atomicAdd(&src_btot[i], hs[i]);
    }
}

__global__ __launch_bounds__(KBUCK) void scan_buckets(
    const int* __restrict__ dst_btot, const int* __restrict__ src_btot,
    int* __restrict__ dst_base, int* __restrict__ src_base,
    int* __restrict__ dst_cursor, int* __restrict__ src_cursor,
    int* __restrict__ row_ptr, int n, int ne) {
    __shared__ int t1[KBUCK], t2[KBUCK];
    const int t = threadIdx.x;
    int v1 = dst_btot[t], v2 = src_btot[t];
    t1[t] = v1; t2[t] = v2;
    for (int off = 1; off < KBUCK; off <<= 1) {
        __syncthreads();
        int a = (t >= off) ? t1[t - off] : 0;
        int b = (t >= off) ? t2[t - off] : 0;
        __syncthreads();
        t1[t] += a; t2[t] += b;
    }
    __syncthreads();
    int e1 = t1[t] - v1, e2 = t2[t] - v2;
    dst_base[t] = e1; src_base[t] = e2;
    dst_cursor[t] = e1; src_cursor[t] = e2;
    if (t == KBUCK - 1) {
        dst_base[KBUCK] = t1[t];
        src_base[KBUCK] = t2[t];
        row_ptr[n] = ne;
    }
}

__global__ __launch_bounds__(256) void partition_dst(
    const int* __restrict__ src, const int* __restrict__ dst, int ne, int D,
    int* __restrict__ dst_cursor, uint2* __restrict__ ebuf) {
    __shared__ int hist[KBUCK];
    __shared__ int gbase[KBUCK];
    const int t = threadIdx.x;
    const int tile0 = blockIdx.x * 4096;

    for (int i = t; i < KBUCK; i += 256) hist[i] = 0;
    __syncthreads();

    int s[16], d[16], r[16];
    #pragma unroll
    for (int j = 0; j < 16; j++) {
        int e = tile0 + j * 256 + t;
        if (e < ne) {
            s[j] = src[e];
            d[j] = dst[e];
            int b = (int)((unsigned)d[j] / (unsigned)D);
            r[j] = atomicAdd(&hist[b], 1);
        }
    }
    __syncthreads();
    for (int i = t; i < KBUCK; i += 256) {
        int c = hist[i];
        gbase[i] = c ? atomicAdd(&dst_cursor[i], c) : 0;
    }
    __syncthreads();
    #pragma unroll
    for (int j = 0; j < 16; j++) {
        int e = tile0 + j * 256 + t;
        if (e < ne) {
            int b = (int)((unsigned)d[j] / (unsigned)D);
            ebuf[gbase[b] + r[j]] = make_uint2((unsigned)s[j], (unsigned)d[j]);
        }
    }
}

__global__ __launch_bounds__(256) void partition_src(
    const int* __restrict__ src, int ne, int D,
    int* __restrict__ src_cursor, unsigned* __restrict__ sbuf) {
    __shared__ int hist[KBUCK];
    __shared__ int gbase[KBUCK];
    const int t = threadIdx.x;
    const int tile0 = blockIdx.x * 4096;

    for (int i = t; i < KBUCK; i += 256) hist[i] = 0;
    __syncthreads();

    int s[16], r[16];
    #pragma unroll
    for (int j = 0; j < 16; j++) {
        int e = tile0 + j * 256 + t;
        if (e < ne) {
            s[j] = src[e];
            int b = (int)((unsigned)s[j] / (unsigned)D);
            r[j] = atomicAdd(&hist[b], 1);
        }
    }
    __syncthreads();
    for (int i = t; i < KBUCK; i += 256) {
        int c = hist[i];
        gbase[i] = c ? atomicAdd(&src_cursor[i], c) : 0;
    }
    __syncthreads();
    #pragma unroll
    for (int j = 0; j < 16; j++) {
        int e = tile0 + j * 256 + t;
        if (e < ne) {
            int b = (int)((unsigned)s[j] / (unsigned)D);
            sbuf[gbase[b] + r[j]] = (unsigned)s[j];
        }
    }
}

// build_dst emits fused CSR entries {src, norm_s[src]} (uint2): one level of random
// indirection in spmm. norm_s built first (build_src launched before build_dst).
__global__ __launch_bounds__(256) void build_dst(
    const uint2* __restrict__ ebuf, const int* __restrict__ dst_base,
    const float* __restrict__ norm_s,
    int n, int D, int* __restrict__ row_ptr, float* __restrict__ norm_d,
    uint2* __restrict__ csr_e) {
    __shared__ int cnt[128], sc[128], rp[128], rank[128];
    const int b = blockIdx.x;
    const int d_lo = b * D;
    if (d_lo >= n) return;
    const int d_hi = (d_lo + D < n) ? d_lo + D : n;
    const int e0 = dst_base[b], e1 = dst_base[b + 1];
    const int t = threadIdx.x;

    if (t < 128) { cnt[t] = 0; rank[t] = 0; }
    __syncthreads();
    for (int i = e0 + t; i < e1; i += 256)
        atomicAdd(&cnt[(int)ebuf[i].y - d_lo], 1);
    __syncthreads();
    if (t < 128) sc[t] = cnt[t];
    __syncthreads();
    for (int off = 1; off < 128; off <<= 1) {
        int v = (t < 128 && t >= off) ? sc[t - off] : 0;
        __syncthreads();
        if (t < 128) sc[t] += v;
        __syncthreads();
    }
    if (t < 128) {
        rp[t] = e0 + sc[t] - cnt[t];   // exclusive
        int d = d_lo + t;
        if (d < d_hi) {
            row_ptr[d] = rp[t];
            norm_d[d] = rsqrtf(fmaxf((float)cnt[t], 1.0f));
        }
    }
    __syncthreads();
    for (int i = e0 + t; i < e1; i += 256) {
        uint2 ed = ebuf[i];
        int dd = (int)ed.y - d_lo;
        int r = atomicAdd(&rank[dd], 1);
        csr_e[rp[dd] + r] = make_uint2(ed.x, __float_as_uint(norm_s[(int)ed.x]));
    }
}

__global__ __launch_bounds__(256) void build_src(
    const unsigned* __restrict__ sbuf, const int* __restrict__ src_base,
    int n, int D, float* __restrict__ norm_s) {
    __shared__ int cnt[128];
    const int b = blockIdx.x;
    const int d_lo = b * D;
    if (d_lo >= n) return;
    const int d_hi = (d_lo + D < n) ? d_lo + D : n;
    const int e0 = src_base[b], e1 = src_base[b + 1];
    const int t = threadIdx.x;
    if (t < 128) cnt[t] = 0;
    __syncthreads();
    for (int i = e0 + t; i < e1; i += 256)
        atomicAdd(&cnt[(int)sbuf[i] - d_lo], 1);
    __syncthreads();
    if (t < 128 && d_lo + t < d_hi)
        norm_s[d_lo + t] = rsqrtf(fmaxf((float)cnt[t], 1.0f));
}

// ---------------- aggregate-first SpMM: U = [norm_d .* (A@(norm_s.*x)) | A@x] ----------------
// Round-11: back to the round-1 shape (one wave per node, 16-edge chunks — 70.6µs
// known-good), but the entry path moves OFF the vector pipes:
//  - entries are wave-uniform -> 16 x s_load_dwordx2 in ONE asm block (+ lgkmcnt(0)
//    inside the block so outputs are genuinely ready): zero VMEM, zero readfirstlane.
//  - invalid edges redirect to zeroed row X[n] with weight 0 via scalar s_cselect:
//    no masking VALU in the inner loop.
//  - gather address = v_lshl_add_u32(sgpr_src, 8, lane*4): 1 VALU/edge, saddr-form
//    load off the X base (32-bit voffset, X spans 25.6MB < 4GB).
// Per-edge cost: 1 VMEM gather + ~7 VALU (6 compute + 1 addr); bookkeeping is SALU.

__global__ __launch_bounds__(256) void spmm_pre(
    const unsigned short* __restrict__ X, const int* __restrict__ row_ptr,
    const uint2* __restrict__ csr_e, const float* __restrict__ norm_d,
    unsigned short* __restrict__ U, int n) {
    const int wid = (blockIdx.x * 256 + threadIdx.x) >> 6;
    const int lane = threadIdx.x & 63;
    if (wid >= n) return;

    const int e0 = __builtin_amdgcn_readfirstlane(row_ptr[wid]);
    const int e1 = __builtin_amdgcn_readfirstlane(row_ptr[wid + 1]);
    const float nd = norm_d[wid];

    float ap0 = 0.f, ap1 = 0.f, as0 = 0.f, as1 = 0.f;
    const unsigned voff = (unsigned)(lane << 2);   // byte offset within row
    const char* Xc = (const char*)X;

    for (int c = e0; c < e1; c += 16) {
        uint64_t E0, E1, E2, E3, E4, E5, E6, E7, E8, E9, Ea, Eb, Ec, Ed, Ee, Ef;
        {
            uint64_t ep = (uint64_t)(const char*)(csr_e + c);
            asm volatile(
                "s_load_dwordx2 %[o0], %[a], 0x0\n\t"
                "s_load_dwordx2 %[o1], %[a], 0x8\n\t"
                "s_load_dwordx2 %[o2], %[a], 0x10\n\t"
                "s_load_dwordx2 %[o3], %[a], 0x18\n\t"
                "s_load_dwordx2 %[o4], %[a], 0x20\n\t"
                "s_load_dwordx2 %[o5], %[a], 0x28\n\t"
                "s_load_dwordx2 %[o6], %[a], 0x30\n\t"
                "s_load_dwordx2 %[o7], %[a], 0x38\n\t"
                "s_load_dwordx2 %[o8], %[a], 0x40\n\t"
                "s_load_dwordx2 %[o9], %[a], 0x48\n\t"
                "s_load_dwordx2 %[oa], %[a], 0x50\n\t"
                "s_load_dwordx2 %[ob], %[a], 0x58\n\t"
                "s_load_dwordx2 %[oc], %[a], 0x60\n\t"
                "s_load_dwordx2 %[od], %[a], 0x68\n\t"
                "s_load_dwordx2 %[oe], %[a], 0x70\n\t"
                "s_load_dwordx2 %[of], %[a], 0x78\n\t"
                "s_waitcnt lgkmcnt(0)"
                : [o0] "=&s"(E0), [o1] "=&s"(E1), [o2] "=&s"(E2), [o3] "=&s"(E3),
                  [o4] "=&s"(E4), [o5] "=&s"(E5), [o6] "=&s"(E6), [o7] "=&s"(E7),
                  [o8] "=&s"(E8), [o9] "=&s"(E9), [oa] "=&s"(Ea), [ob] "=&s"(Eb),
                  [oc] "=&s"(Ec), [od] "=&s"(Ed), [oe] "=&s"(Ee), [of] "=&s"(Ef)
                : [a] "s"(ep)
                : "memory");
        }

        unsigned q[16];
        float wv[16];

#define PREP(i, Ei)                                                             \
        {                                                                       \
            int sv = (int)(unsigned)(Ei);                                       \
            unsigned wu = (unsigned)((Ei) >> 32);                               \
            const bool val = (c + i) < e1;      /* wave-uniform scalar */       \
            sv = val ? sv : n;                  /* s_cselect */                 \
            wu = val ? wu : 0u;                 /* s_cselect */                 \
            wv[i] = u2f(wu);                                                    \
            unsigned off = (((unsigned)sv) << 8) + voff;  /* v_lshl_add_u32 */  \
            q[i] = *(const unsigned*)(Xc + off);          /* saddr-form load */ \
        }
        PREP(0, E0)  PREP(1, E1)  PREP(2, E2)  PREP(3, E3)
        PREP(4, E4)  PREP(5, E5)  PREP(6, E6)  PREP(7, E7)
        PREP(8, E8)  PREP(9, E9)  PREP(10, Ea) PREP(11, Eb)
        PREP(12, Ec) PREP(13, Ed) PREP(14, Ee) PREP(15, Ef)
#undef PREP

        #pragma unroll
        for (int i = 0; i < 16; i++) {
            unsigned qq = q[i];
            float x0 = u2f(qq << 16);
            float x1 = u2f(qq & 0xffff0000u);
            ap0 += x0; ap1 += x1;
            as0 = fmaf(wv[i], x0, as0);
            as1 = fmaf(wv[i], x1, as1);
        }
    }

    ushort2 gc, rs;
    gc.x = f2bf(nd * as0); gc.y = f2bf(nd * as1);
    rs.x = f2bf(ap0);      rs.y = f2bf(ap1);
    unsigned short* Ur = U + (size_t)wid * 256;
    *(ushort2*)(Ur + lane * 2) = gc;
    *(ushort2*)(Ur + 128 + lane * 2) = rs;
}

// ---------------- MFMA GEMM: y = U @ [W;R] + b (+relu), K=256 ----------------
// U: [M,256] bf16. Wf: fragment-major bf16 (prep_wf2). Block = 4 waves; wave w does
// rows blockIdx.x*64 + w*16, all NCOL cols. A (16x256) = 8 bf16x8 frags in registers.
// mfma_f32_16x16x32_bf16 layouts (HW-verified m89/m91): A[m=lane&15][k=(lane>>4)*8+j],
// C/D col=lane&15, row=(lane>>4)*4+reg.

template <int NCOL, bool RELU, bool OUT_BF16>
__global__ __launch_bounds__(256) void gemm_mfma(
    const unsigned short* __restrict__ U, int M,
    const unsigned short* __restrict__ Wf,
    const float* __restrict__ bias, void* __restrict__ outv) {
    constexpr int NT = NCOL / 16;
    __shared__ unsigned short Bs[256 * NCOL];

    const int t = threadIdx.x;
    const int wave = t >> 6, lane = t & 63;
    const int r0 = blockIdx.x * 64 + wave * 16;

    // stage Wf -> LDS (contiguous 16B copies, conflict-free)
    constexpr int TOT16 = 256 * NCOL * 2 / 16;
    const uint4* gsrc = (const uint4*)Wf;
    uint4* ldst = (uint4*)Bs;
    for (int i = t; i < TOT16; i += 256) ldst[i] = gsrc[i];

    // A fragments (rows am = r0 + (lane&15), k = kb*32 + (lane>>4)*8 + j)
    const int am = r0 + (lane & 15);
    const int kq = (lane >> 4) * 8;
    bf16x8 afrag[8];
    if (am < M) {
        const unsigned short* ap = U + (size_t)am * 256 + kq;
        #pragma unroll
        for (int kb = 0; kb < 8; kb++)
            afrag[kb] = *(const bf16x8*)(ap + kb * 32);
    } else {
        #pragma unroll
        for (int kb = 0; kb < 8; kb++) afrag[kb] = bf16x8{};
    }

    const int orow = r0 + (lane >> 4) * 4;
    __syncthreads();

    #pragma unroll 1
    for (int nt = 0; nt < NT; nt++) {
        f32x4 acc = {0.f, 0.f, 0.f, 0.f};
        #pragma unroll
        for (int kb = 0; kb < 8; kb++) {
            bf16x8 b = *(const bf16x8*)(Bs + ((kb * NT + nt) * 64 + lane) * 8);
            acc = __builtin_amdgcn_mfma_f32_16x16x32_bf16(afrag[kb], b, acc, 0, 0, 0);
        }
        const int gcol = nt * 16 + (lane & 15);
        const float bv = bias[gcol];
        #pragma unroll
        for (int r = 0; r < 4; r++) {
            int gm = orow + r;
            if (gm < M) {
                float v = acc[r] + bv;
                if (RELU) v = fmaxf(v, 0.f);
                if constexpr (OUT_BF16)
                    ((unsigned short*)outv)[(size_t)gm * NCOL + gcol] = f2bf(v);
                else
                    ((float*)outv)[(size_t)gm * NCOL + gcol] = v;
            }
        }
    }
}

// ---------------- launch ----------------

extern "C" void kernel_launch(void* const* d_in, const int* in_sizes, int n_in,
                              void* d_out, int out_size, void* d_ws, size_t ws_size,
                              hipStream_t stream) {
    const float* raw_x  = (const float*)d_in[0];
    const int*   src    = (const int*)d_in[1];
    const int*   dst    = (const int*)d_in[2];
    const float* gc_w0  = (const float*)d_in[3];
    const float* gc_b0  = (const float*)d_in[4];
    const float* gc_w1  = (const float*)d_in[5];
    const float* gc_b1  = (const float*)d_in[6];
    const float* gc_w2  = (const float*)d_in[7];
    const float* gc_b2  = (const float*)d_in[8];
    const float* res_w0 = (const float*)d_in[9];
    const float* res_w1 = (const float*)d_in[10];
    const float* res_w2 = (const float*)d_in[11];

    const int n  = in_sizes[0] / NFEAT;   // 100000
    const int ne = in_sizes[1];           // 1600000
    float* out = (float*)d_out;
    const int D = (n + KBUCK - 1) / KBUCK;   // nodes per bucket (98, <=128)

    // workspace layout (Xb/X1b have an extra zeroed row n; csr_e has 48 slack entries)
    char* w = (char*)d_ws;
    unsigned short* U   = (unsigned short*)w; w += (size_t)n * 256 * sizeof(unsigned short);       // 51.2 MB
    unsigned short* Xb  = (unsigned short*)w; w += (size_t)(n + 1) * 128 * sizeof(unsigned short); // 25.6 MB
    unsigned short* X1b = (unsigned short*)w; w += (size_t)(n + 1) * 128 * sizeof(unsigned short); // 25.6 MB
    float* norm_s = (float*)w;   w += (size_t)n * sizeof(float);
    float* norm_d = (float*)w;   w += (size_t)n * sizeof(float);
    int* row_ptr = (int*)w;      w += (size_t)(n + 1) * sizeof(int);
    uint2* csr_e = (uint2*)w;    w += (size_t)(ne + 48) * sizeof(uint2);   // 12.8 MB {src, ns}
    uint2* ebuf = (uint2*)w;     w += (size_t)ne * sizeof(uint2);          // 12.8 MB
    unsigned* sbuf = (unsigned*)w; w += (size_t)ne * sizeof(unsigned);     // 6.4 MB
    int* dst_btot = (int*)w;     w += KBUCK * sizeof(int);
    int* src_btot = (int*)w;     w += KBUCK * sizeof(int);
    int* dst_base = (int*)w;     w += (KBUCK + 1) * sizeof(int);
    int* src_base = (int*)w;     w += (KBUCK + 1) * sizeof(int);
    int* dst_cursor = (int*)w;   w += KBUCK * sizeof(int);
    int* src_cursor = (int*)w;   w += KBUCK * sizeof(int);
    unsigned short* Wf0 = (unsigned short*)w; w += 256 * 128 * sizeof(unsigned short);
    unsigned short* Wf1 = (unsigned short*)w; w += 256 * 128 * sizeof(unsigned short);
    unsigned short* Wf2 = (unsigned short*)w; w += 256 * 64 * sizeof(unsigned short);

    const int tiles = (ne + 4095) / 4096;

    // --- preprocessing: bf16 cast, weight fragments, bucketed CSR + degrees ---
    cast_bf16_kernel<<<(n * (NFEAT / 4) + 255) / 256, 256, 0, stream>>>(raw_x, Xb, n * (NFEAT / 4));
    // zero row n of Xb and X1b (spmm pad-redirect target), and csr_e slack entries
    zero_ints<<<1, 64, 0, stream>>>((int*)(Xb + (size_t)n * 128), 64);
    zero_ints<<<1, 64, 0, stream>>>((int*)(X1b + (size_t)n * 128), 64);
    zero_ints<<<1, 96, 0, stream>>>((int*)(csr_e + ne), 96);
    prep_wf2<128><<<128, 256, 0, stream>>>(gc_w0, res_w0, Wf0);
    prep_wf2<128><<<128, 256, 0, stream>>>(gc_w1, res_w1, Wf1);
    prep_wf2<64><<<64, 256, 0, stream>>>(gc_w2, res_w2, Wf2);
    zero_ints<<<(2 * KBUCK + 255) / 256, 256, 0, stream>>>(dst_btot, 2 * KBUCK); // dst_btot+src_btot contiguous
    hist_kernel<<<tiles, 256, 0, stream>>>(src, dst, ne, D, dst_btot, src_btot);
    scan_buckets<<<1, KBUCK, 0, stream>>>(dst_btot, src_btot, dst_base, src_base,
                                          dst_cursor, src_cursor, row_ptr, n, ne);
    partition_dst<<<tiles, 256, 0, stream>>>(src, dst, ne, D, dst_cursor, ebuf);
    partition_src<<<tiles, 256, 0, stream>>>(src, ne, D, src_cursor, sbuf);
    build_src<<<KBUCK, 256, 0, stream>>>(sbuf, src_base, n, D, norm_s);
    build_dst<<<KBUCK, 256, 0, stream>>>(ebuf, dst_base, norm_s, n, D, row_ptr, norm_d, csr_e);

    const int gemm_blocks = (n + 63) / 64;
    const int spmm_blocks = (n + 3) / 4;   // one wave per node

    // --- layer 0: x1 = relu([nd*A(ns*x) | A x] @ [W0;R0] + b0) ---
    spmm_pre<<<spmm_blocks, 256, 0, stream>>>(Xb, row_ptr, csr_e, norm_d, U, n);
    gemm_mfma<128, true, true><<<gemm_blocks, 256, 0, stream>>>(U, n, Wf0, gc_b0, X1b);

    // --- layer 1 ---
    spmm_pre<<<spmm_blocks, 256, 0, stream>>>(X1b, row_ptr, csr_e, norm_d, U, n);
    gemm_mfma<128, true, true><<<gemm_blocks, 256, 0, stream>>>(U, n, Wf1, gc_b1, X1b);

    // --- layer 2: output 64-wide fp32, no relu ---
    spmm_pre<<<spmm_blocks, 256, 0, stream>>>(X1b, row_ptr, csr_e, norm_d, U, n);
    gemm_mfma<64, false, false><<<gemm_blocks, 256, 0, stream>>>(U, n, Wf2, gc_b2, out);
}

// Round 4
// 491.104 us; speedup vs baseline: 1.3048x; 1.0632x over previous
//
#include <hip/hip_runtime.h>
#include <cstdint>
#include <cstddef>

#define NFEAT 128
#define KBUCK 1024

typedef __attribute__((ext_vector_type(8))) short bf16x8;
typedef __attribute__((ext_vector_type(4))) float f32x4;
typedef __attribute__((ext_vector_type(2))) float f32x2;

// bf16 <-> f32 helpers (RNE, no NaN handling needed — activations are finite)
__device__ __forceinline__ unsigned short f2bf(float x) {
    union { float f; unsigned u; } v; v.f = x;
    unsigned r = v.u + 0x7fffu + ((v.u >> 16) & 1u);
    return (unsigned short)(r >> 16);
}
__device__ __forceinline__ float bf2f(unsigned short b) {
    union { unsigned u; float f; } v; v.u = ((unsigned)b) << 16;
    return v.f;
}
__device__ __forceinline__ float u2f(unsigned u) {
    union { unsigned u; float f; } v; v.u = u; return v.f;
}
// pack two f32 -> dword of 2 bf16 (RNE) in one instruction
__device__ __forceinline__ unsigned cvtpk_bf16(float lo, float hi) {
    unsigned r;
    asm("v_cvt_pk_bf16_f32 %0, %1, %2" : "=v"(r) : "v"(lo), "v"(hi));
    return r;
}

// ---------------- preprocessing kernels ----------------

__global__ void zero_ints(int* __restrict__ p, int n) {
    int i = blockIdx.x * blockDim.x + threadIdx.x;
    if (i < n) p[i] = 0;
}

__global__ void cast_bf16_kernel(const float* __restrict__ x, unsigned short* __restrict__ y, int n4) {
    int i = blockIdx.x * blockDim.x + threadIdx.x;
    if (i < n4) {
        float4 v = ((const float4*)x)[i];
        ushort4 o;
        o.x = f2bf(v.x); o.y = f2bf(v.y); o.z = f2bf(v.z); o.w = f2bf(v.w);
        ((ushort4*)y)[i] = o;
    }
}

// Pack Wcat (256 x NCOL: rows 0..127 = gcW, 128..255 = resW; fp32) into bf16 MFMA
// B-fragment order for K=256 GEMM:
// Wf[((kb*NT + nt)*64 + lane)*8 + j] = Wcat[kb*32 + (lane>>4)*8 + j][nt*16 + (lane&15)]
template <int NCOL>
__global__ void prep_wf2(const float* __restrict__ gcW, const float* __restrict__ resW,
                         unsigned short* __restrict__ Wf) {
    constexpr int NT = NCOL / 16;
    int tid = blockIdx.x * 256 + threadIdx.x;
    if (tid >= 256 * NCOL) return;
    int k = tid / NCOL, c = tid % NCOL;
    float v = (k < 128) ? gcW[k * NCOL + c] : resW[(k - 128) * NCOL + c];
    int kb = k >> 5, koff = k & 31, quad = koff >> 3, j = koff & 7;
    int nt = c >> 4, ncol = c & 15, lane = quad * 16 + ncol;
    Wf[((kb * NT + nt) * 64 + lane) * 8 + j] = f2bf(v);
}

// ---------------- fully-bucketed graph preprocessing ----------------

__global__ __launch_bounds__(256) void hist_kernel(
    const int* __restrict__ src, const int* __restrict__ dst, int ne, int D,
    int* __restrict__ dst_btot, int* __restrict__ src_btot) {
    __shared__ int hd[KBUCK], hs[KBUCK];
    const int t = threadIdx.x;
    const int tile0 = blockIdx.x * 4096;
    for (int i = t; i < KBUCK; i += 256) { hd[i] = 0; hs[i] = 0; }
    __syncthreads();
    #pragma unroll
    for (int j = 0; j < 16; j++) {
        int e = tile0 + j * 256 + t;
        if (e < ne) {
            atomicAdd(&hd[(unsigned)dst[e] / (unsigned)D], 1);
            atomicAdd(&hs[(unsigned)src[e] / (unsigned)D], 1);
        }
    }
    __syncthreads();
    for (int i = t; i < KBUCK; i += 256) {
        if (hd[i]) atomicAdd(&dst_btot[i], hd[i]);
        if (hs[i]) atomicAdd(&src_btot[i], hs[i]);
    }
}

__global__ __launch_bounds__(KBUCK) void scan_buckets(
    const int* __restrict__ dst_btot, const int* __restrict__ src_btot,
    int* __restrict__ dst_base, int* __restrict__ src_base,
    int* __restrict__ dst_cursor, int* __restrict__ src_cursor,
    int* __restrict__ row_ptr, int n, int ne) {
    __shared__ int t1[KBUCK], t2[KBUCK];
    const int t = threadIdx.x;
    int v1 = dst_btot[t], v2 = src_btot[t];
    t1[t] = v1; t2[t] = v2;
    for (int off = 1; off < KBUCK; off <<= 1) {
        __syncthreads();
        int a = (t >= off) ? t1[t - off] : 0;
        int b = (t >= off) ? t2[t - off] : 0;
        __syncthreads();
        t1[t] += a; t2[t] += b;
    }
    __syncthreads();
    int e1 = t1[t] - v1, e2 = t2[t] - v2;
    dst_base[t] = e1; src_base[t] = e2;
    dst_cursor[t] = e1; src_cursor[t] = e2;
    if (t == KBUCK - 1) {
        dst_base[KBUCK] = t1[t];
        src_base[KBUCK] = t2[t];
        row_ptr[n] = ne;
    }
}

// merged dst+src partition: one pass over (src,dst), writes both ebuf and sbuf.
__global__ __launch_bounds__(256) void partition_both(
    const int* __restrict__ src, const int* __restrict__ dst, int ne, int D,
    int* __restrict__ dst_cursor, int* __restrict__ src_cursor,
    uint2* __restrict__ ebuf, unsigned* __restrict__ sbuf) {
    __shared__ int hd[KBUCK], hs[KBUCK];
    __shared__ int gbd[KBUCK], gbs[KBUCK];
    const int t = threadIdx.x;
    const int tile0 = blockIdx.x * 4096;

    for (int i = t; i < KBUCK; i += 256) { hd[i] = 0; hs[i] = 0; }
    __syncthreads();

    int s[16], d[16], rd[16], rs[16];
    #pragma unroll
    for (int j = 0; j < 16; j++) {
        int e = tile0 + j * 256 + t;
        if (e < ne) {
            s[j] = src[e];
            d[j] = dst[e];
            rd[j] = atomicAdd(&hd[(unsigned)d[j] / (unsigned)D], 1);
            rs[j] = atomicAdd(&hs[(unsigned)s[j] / (unsigned)D], 1);
        }
    }
    __syncthreads();
    for (int i = t; i < KBUCK; i += 256) {
        int c1 = hd[i]; gbd[i] = c1 ? atomicAdd(&dst_cursor[i], c1) : 0;
        int c2 = hs[i]; gbs[i] = c2 ? atomicAdd(&src_cursor[i], c2) : 0;
    }
    __syncthreads();
    #pragma unroll
    for (int j = 0; j < 16; j++) {
        int e = tile0 + j * 256 + t;
        if (e < ne) {
            ebuf[gbd[(unsigned)d[j] / (unsigned)D] + rd[j]] = make_uint2((unsigned)s[j], (unsigned)d[j]);
            sbuf[gbs[(unsigned)s[j] / (unsigned)D] + rs[j]] = (unsigned)s[j];
        }
    }
}

// build_dst emits fused CSR entries {src, norm_s[src]} (uint2): one level of random
// indirection in spmm. norm_s built first (build_src launched before build_dst).
__global__ __launch_bounds__(256) void build_dst(
    const uint2* __restrict__ ebuf, const int* __restrict__ dst_base,
    const float* __restrict__ norm_s,
    int n, int D, int* __restrict__ row_ptr, float* __restrict__ norm_d,
    uint2* __restrict__ csr_e) {
    __shared__ int cnt[128], sc[128], rp[128], rank[128];
    const int b = blockIdx.x;
    const int d_lo = b * D;
    if (d_lo >= n) return;
    const int d_hi = (d_lo + D < n) ? d_lo + D : n;
    const int e0 = dst_base[b], e1 = dst_base[b + 1];
    const int t = threadIdx.x;

    if (t < 128) { cnt[t] = 0; rank[t] = 0; }
    __syncthreads();
    for (int i = e0 + t; i < e1; i += 256)
        atomicAdd(&cnt[(int)ebuf[i].y - d_lo], 1);
    __syncthreads();
    if (t < 128) sc[t] = cnt[t];
    __syncthreads();
    for (int off = 1; off < 128; off <<= 1) {
        int v = (t < 128 && t >= off) ? sc[t - off] : 0;
        __syncthreads();
        if (t < 128) sc[t] += v;
        __syncthreads();
    }
    if (t < 128) {
        rp[t] = e0 + sc[t] - cnt[t];   // exclusive
        int d = d_lo + t;
        if (d < d_hi) {
            row_ptr[d] = rp[t];
            norm_d[d] = rsqrtf(fmaxf((float)cnt[t], 1.0f));
        }
    }
    __syncthreads();
    for (int i = e0 + t; i < e1; i += 256) {
        uint2 ed = ebuf[i];
        int dd = (int)ed.y - d_lo;
        int r = atomicAdd(&rank[dd], 1);
        csr_e[rp[dd] + r] = make_uint2(ed.x, __float_as_uint(norm_s[(int)ed.x]));
    }
}

__global__ __launch_bounds__(256) void build_src(
    const unsigned* __restrict__ sbuf, const int* __restrict__ src_base,
    int n, int D, float* __restrict__ norm_s) {
    __shared__ int cnt[128];
    const int b = blockIdx.x;
    const int d_lo = b * D;
    if (d_lo >= n) return;
    const int d_hi = (d_lo + D < n) ? d_lo + D : n;
    const int e0 = src_base[b], e1 = src_base[b + 1];
    const int t = threadIdx.x;
    if (t < 128) cnt[t] = 0;
    __syncthreads();
    for (int i = e0 + t; i < e1; i += 256)
        atomicAdd(&cnt[(int)sbuf[i] - d_lo], 1);
    __syncthreads();
    if (t < 128 && d_lo + t < d_hi)
        norm_s[d_lo + t] = rsqrtf(fmaxf((float)cnt[t], 1.0f));
}

// ---------------- aggregate-first SpMM: U = [norm_d .* (A@(norm_s.*x)) | A@x] ----------------
// Round-12: QUAD-ROW gather. Lanes split 4 groups x 16; group g reads 16B/lane of
// edge (4j+g)'s row — one VMEM instruction covers FOUR rows (1KB), cutting VMEM
// instructions per edge 1 -> 0.25. Entries arrive via ONE vector load
// csr_e[c + (lane&15)], are sanitized with 2 cndmask (invalid -> zero row n,
// weight 0), and distributed to quad slots by ds_bpermute with LOOP-INVARIANT
// indices (precomputed; no per-chunk scalar machinery — round-2 lesson).
// Epilogue: shfl_xor(16/32) cross-group reduce + v_cvt_pk_bf16_f32 pack.

__global__ __launch_bounds__(256) void spmm_pre(
    const unsigned short* __restrict__ X, const int* __restrict__ row_ptr,
    const uint2* __restrict__ csr_e, const float* __restrict__ norm_d,
    unsigned short* __restrict__ U, int n) {
    const int wid = (blockIdx.x * 256 + threadIdx.x) >> 6;
    const int lane = threadIdx.x & 63;
    if (wid >= n) return;

    const int e0 = __builtin_amdgcn_readfirstlane(row_ptr[wid]);
    const int e1 = __builtin_amdgcn_readfirstlane(row_ptr[wid + 1]);
    const float nd = norm_d[wid];

    const int g = lane >> 4, li = lane & 15;
    const unsigned vbyte = (unsigned)li << 4;            // 16B block within row
    const char* Xc = (const char*)X;
    // loop-invariant bpermute byte-indices: entry (4j+g) lives in lane (4j+g)
    const int bi0 = g * 4, bi1 = bi0 + 16, bi2 = bi0 + 32, bi3 = bi0 + 48;

    f32x2 ap[4], as[4];
    #pragma unroll
    for (int k = 0; k < 4; k++) { ap[k] = f32x2{0.f, 0.f}; as[k] = f32x2{0.f, 0.f}; }

    for (int c = e0; c < e1; c += 16) {
        // one vector entry load; sanitize (beyond-row entries -> zero row, weight 0)
        uint2 E = csr_e[c + li];
        const bool val = (c + li) < e1;
        int srow = val ? (int)E.x : n;
        int wbit = val ? (int)E.y : 0;

        // distribute to quad slots (LDS-pipe, no VALU tree)
        int r0 = __builtin_amdgcn_ds_bpermute(bi0, srow);
        int w0 = __builtin_amdgcn_ds_bpermute(bi0, wbit);
        int r1 = __builtin_amdgcn_ds_bpermute(bi1, srow);
        int w1 = __builtin_amdgcn_ds_bpermute(bi1, wbit);
        int r2 = __builtin_amdgcn_ds_bpermute(bi2, srow);
        int w2 = __builtin_amdgcn_ds_bpermute(bi2, wbit);
        int r3 = __builtin_amdgcn_ds_bpermute(bi3, srow);
        int w3 = __builtin_amdgcn_ds_bpermute(bi3, wbit);

        // four quad-row gathers (each: 64 lanes x 16B = 4 rows x 256B)
        uint4 q0 = *(const uint4*)(Xc + ((((unsigned)r0) << 8) + vbyte));
        uint4 q1 = *(const uint4*)(Xc + ((((unsigned)r1) << 8) + vbyte));
        uint4 q2 = *(const uint4*)(Xc + ((((unsigned)r2) << 8) + vbyte));
        uint4 q3 = *(const uint4*)(Xc + ((((unsigned)r3) << 8) + vbyte));

#define ACC(Q, WB)                                                              \
        {                                                                       \
            float wv = u2f((unsigned)(WB));                                     \
            f32x2 w2 = {wv, wv};                                                \
            f32x2 x0 = {u2f((Q).x << 16), u2f((Q).x & 0xffff0000u)};            \
            f32x2 x1 = {u2f((Q).y << 16), u2f((Q).y & 0xffff0000u)};            \
            f32x2 x2 = {u2f((Q).z << 16), u2f((Q).z & 0xffff0000u)};            \
            f32x2 x3 = {u2f((Q).w << 16), u2f((Q).w & 0xffff0000u)};            \
            ap[0] += x0; ap[1] += x1; ap[2] += x2; ap[3] += x3;                 \
            as[0] = w2 * x0 + as[0]; as[1] = w2 * x1 + as[1];                   \
            as[2] = w2 * x2 + as[2]; as[3] = w2 * x3 + as[3];                   \
        }
        ACC(q0, w0) ACC(q1, w1) ACC(q2, w2) ACC(q3, w3)
#undef ACC
    }

    // reduce across the 4 lane-groups (xor 16 then 32)
    #pragma unroll
    for (int k = 0; k < 4; k++) {
        #pragma unroll
        for (int comp = 0; comp < 2; comp++) {
            float a = ap[k][comp];
            a += __shfl_xor(a, 16); a += __shfl_xor(a, 32);
            ap[k][comp] = a;
            float s = as[k][comp];
            s += __shfl_xor(s, 16); s += __shfl_xor(s, 32);
            as[k][comp] = s;
        }
    }

    unsigned short* Ur = U + (size_t)wid * 256;
    if (g == 0) {            // gc half: cols 8li..8li+7 at bytes [li*16 .. )
        uint4 o;
        o.x = cvtpk_bf16(nd * as[0][0], nd * as[0][1]);
        o.y = cvtpk_bf16(nd * as[1][0], nd * as[1][1]);
        o.z = cvtpk_bf16(nd * as[2][0], nd * as[2][1]);
        o.w = cvtpk_bf16(nd * as[3][0], nd * as[3][1]);
        *(uint4*)((char*)Ur + vbyte) = o;
    } else if (g == 1) {     // rs half at bytes [256 + li*16 .. )
        uint4 o;
        o.x = cvtpk_bf16(ap[0][0], ap[0][1]);
        o.y = cvtpk_bf16(ap[1][0], ap[1][1]);
        o.z = cvtpk_bf16(ap[2][0], ap[2][1]);
        o.w = cvtpk_bf16(ap[3][0], ap[3][1]);
        *(uint4*)((char*)Ur + 256 + vbyte) = o;
    }
}

// ---------------- MFMA GEMM: y = U @ [W;R] + b (+relu), K=256 ----------------
// Round-12: NO LDS staging — Wf is 64KB and L2-resident; B-fragments load straight
// from global per MFMA (removes the per-block 64KB restage, the barrier, and the
// 2-blocks/CU LDS occupancy cap). U: [M,256] bf16; Wf fragment-major (prep_wf2).
// mfma_f32_16x16x32_bf16 layouts (HW-verified m89/m91): A[m=lane&15][k=(lane>>4)*8+j],
// C/D col=lane&15, row=(lane>>4)*4+reg.

template <int NCOL, bool RELU, bool OUT_BF16>
__global__ __launch_bounds__(256) void gemm_mfma(
    const unsigned short* __restrict__ U, int M,
    const unsigned short* __restrict__ Wf,
    const float* __restrict__ bias, void* __restrict__ outv) {
    constexpr int NT = NCOL / 16;

    const int t = threadIdx.x;
    const int wave = t >> 6, lane = t & 63;
    const int r0 = blockIdx.x * 64 + wave * 16;

    // A fragments (rows am = r0 + (lane&15), k = kb*32 + (lane>>4)*8 + j)
    const int am = r0 + (lane & 15);
    const int kq = (lane >> 4) * 8;
    bf16x8 afrag[8];
    if (am < M) {
        const unsigned short* ap = U + (size_t)am * 256 + kq;
        #pragma unroll
        for (int kb = 0; kb < 8; kb++)
            afrag[kb] = *(const bf16x8*)(ap + kb * 32);
    } else {
        #pragma unroll
        for (int kb = 0; kb < 8; kb++) afrag[kb] = bf16x8{};
    }

    const int orow = r0 + (lane >> 4) * 4;
    const bf16x8* Wv = (const bf16x8*)Wf;

    #pragma unroll 1
    for (int nt = 0; nt < NT; nt++) {
        f32x4 acc = {0.f, 0.f, 0.f, 0.f};
        #pragma unroll
        for (int kb = 0; kb < 8; kb++) {
            bf16x8 b = Wv[(kb * NT + nt) * 64 + lane];
            acc = __builtin_amdgcn_mfma_f32_16x16x32_bf16(afrag[kb], b, acc, 0, 0, 0);
        }
        const int gcol = nt * 16 + (lane & 15);
        const float bv = bias[gcol];
        #pragma unroll
        for (int r = 0; r < 4; r++) {
            int gm = orow + r;
            if (gm < M) {
                float v = acc[r] + bv;
                if (RELU) v = fmaxf(v, 0.f);
                if constexpr (OUT_BF16)
                    ((unsigned short*)outv)[(size_t)gm * NCOL + gcol] = f2bf(v);
                else
                    ((float*)outv)[(size_t)gm * NCOL + gcol] = v;
            }
        }
    }
}

// ---------------- launch ----------------

extern "C" void kernel_launch(void* const* d_in, const int* in_sizes, int n_in,
                              void* d_out, int out_size, void* d_ws, size_t ws_size,
                              hipStream_t stream) {
    const float* raw_x  = (const float*)d_in[0];
    const int*   src    = (const int*)d_in[1];
    const int*   dst    = (const int*)d_in[2];
    const float* gc_w0  = (const float*)d_in[3];
    const float* gc_b0  = (const float*)d_in[4];
    const float* gc_w1  = (const float*)d_in[5];
    const float* gc_b1  = (const float*)d_in[6];
    const float* gc_w2  = (const float*)d_in[7];
    const float* gc_b2  = (const float*)d_in[8];
    const float* res_w0 = (const float*)d_in[9];
    const float* res_w1 = (const float*)d_in[10];
    const float* res_w2 = (const float*)d_in[11];

    const int n  = in_sizes[0] / NFEAT;   // 100000
    const int ne = in_sizes[1];           // 1600000
    float* out = (float*)d_out;
    const int D = (n + KBUCK - 1) / KBUCK;   // nodes per bucket (98, <=128)

    // workspace layout (Xb/X1b have an extra zeroed row n; csr_e has 48 slack entries)
    char* w = (char*)d_ws;
    unsigned short* U   = (unsigned short*)w; w += (size_t)n * 256 * sizeof(unsigned short);       // 51.2 MB
    unsigned short* Xb  = (unsigned short*)w; w += (size_t)(n + 1) * 128 * sizeof(unsigned short); // 25.6 MB
    unsigned short* X1b = (unsigned short*)w; w += (size_t)(n + 1) * 128 * sizeof(unsigned short); // 25.6 MB
    float* norm_s = (float*)w;   w += (size_t)n * sizeof(float);
    float* norm_d = (float*)w;   w += (size_t)n * sizeof(float);
    int* row_ptr = (int*)w;      w += (size_t)(n + 1) * sizeof(int);
    uint2* csr_e = (uint2*)w;    w += (size_t)(ne + 48) * sizeof(uint2);   // 12.8 MB {src, ns}
    uint2* ebuf = (uint2*)w;     w += (size_t)ne * sizeof(uint2);          // 12.8 MB
    unsigned* sbuf = (unsigned*)w; w += (size_t)ne * sizeof(unsigned);     // 6.4 MB
    int* dst_btot = (int*)w;     w += KBUCK * sizeof(int);
    int* src_btot = (int*)w;     w += KBUCK * sizeof(int);
    int* dst_base = (int*)w;     w += (KBUCK + 1) * sizeof(int);
    int* src_base = (int*)w;     w += (KBUCK + 1) * sizeof(int);
    int* dst_cursor = (int*)w;   w += KBUCK * sizeof(int);
    int* src_cursor = (int*)w;   w += KBUCK * sizeof(int);
    unsigned short* Wf0 = (unsigned short*)w; w += 256 * 128 * sizeof(unsigned short);
    unsigned short* Wf1 = (unsigned short*)w; w += 256 * 128 * sizeof(unsigned short);
    unsigned short* Wf2 = (unsigned short*)w; w += 256 * 64 * sizeof(unsigned short);

    const int tiles = (ne + 4095) / 4096;

    // --- preprocessing: bf16 cast, weight fragments, bucketed CSR + degrees ---
    cast_bf16_kernel<<<(n * (NFEAT / 4) + 255) / 256, 256, 0, stream>>>(raw_x, Xb, n * (NFEAT / 4));
    // zero row n of Xb and X1b (spmm pad-redirect target), and csr_e slack entries
    zero_ints<<<1, 64, 0, stream>>>((int*)(Xb + (size_t)n * 128), 64);
    zero_ints<<<1, 64, 0, stream>>>((int*)(X1b + (size_t)n * 128), 64);
    zero_ints<<<1, 96, 0, stream>>>((int*)(csr_e + ne), 96);
    prep_wf2<128><<<128, 256, 0, stream>>>(gc_w0, res_w0, Wf0);
    prep_wf2<128><<<128, 256, 0, stream>>>(gc_w1, res_w1, Wf1);
    prep_wf2<64><<<64, 256, 0, stream>>>(gc_w2, res_w2, Wf2);
    zero_ints<<<(2 * KBUCK + 255) / 256, 256, 0, stream>>>(dst_btot, 2 * KBUCK); // dst_btot+src_btot contiguous
    hist_kernel<<<tiles, 256, 0, stream>>>(src, dst, ne, D, dst_btot, src_btot);
    scan_buckets<<<1, KBUCK, 0, stream>>>(dst_btot, src_btot, dst_base, src_base,
                                          dst_cursor, src_cursor, row_ptr, n, ne);
    partition_both<<<tiles, 256, 0, stream>>>(src, dst, ne, D, dst_cursor, src_cursor, ebuf, sbuf);
    build_src<<<KBUCK, 256, 0, stream>>>(sbuf, src_base, n, D, norm_s);
    build_dst<<<KBUCK, 256, 0, stream>>>(ebuf, dst_base, norm_s, n, D, row_ptr, norm_d, csr_e);

    const int gemm_blocks = (n + 63) / 64;
    const int spmm_blocks = (n + 3) / 4;   // one wave per node

    // --- layer 0: x1 = relu([nd*A(ns*x) | A x] @ [W0;R0] + b0) ---
    spmm_pre<<<spmm_blocks, 256, 0, stream>>>(Xb, row_ptr, csr_e, norm_d, U, n);
    gemm_mfma<128, true, true><<<gemm_blocks, 256, 0, stream>>>(U, n, Wf0, gc_b0, X1b);

    // --- layer 1 ---
    spmm_pre<<<spmm_blocks, 256, 0, stream>>>(X1b, row_ptr, csr_e, norm_d, U, n);
    gemm_mfma<128, true, true><<<gemm_blocks, 256, 0, stream>>>(U, n, Wf1, gc_b1, X1b);

    // --- layer 2: output 64-wide fp32, no relu ---
    spmm_pre<<<spmm_blocks, 256, 0, stream>>>(X1b, row_ptr, csr_e, norm_d, U, n);
    gemm_mfma<64, false, false><<<gemm_blocks, 256, 0, stream>>>(U, n, Wf2, gc_b2, out);
}

// Round 5
// 488.203 us; speedup vs baseline: 1.3126x; 1.0059x over previous
//
#include <hip/hip_runtime.h>
#include <cstdint>
#include <cstddef>

#define NFEAT 128
#define KBUCK 1024

typedef __attribute__((ext_vector_type(8))) short bf16x8;
typedef __attribute__((ext_vector_type(4))) float f32x4;

// bf16 <-> f32 helpers (RNE, no NaN handling needed — activations are finite)
__device__ __forceinline__ unsigned short f2bf(float x) {
    union { float f; unsigned u; } v; v.f = x;
    unsigned r = v.u + 0x7fffu + ((v.u >> 16) & 1u);
    return (unsigned short)(r >> 16);
}
__device__ __forceinline__ float bf2f(unsigned short b) {
    union { unsigned u; float f; } v; v.u = ((unsigned)b) << 16;
    return v.f;
}
__device__ __forceinline__ float u2f(unsigned u) {
    union { unsigned u; float f; } v; v.u = u; return v.f;
}

// ---------------- preprocessing kernels ----------------

__global__ void zero_ints(int* __restrict__ p, int n) {
    int i = blockIdx.x * blockDim.x + threadIdx.x;
    if (i < n) p[i] = 0;
}

__global__ void cast_bf16_kernel(const float* __restrict__ x, unsigned short* __restrict__ y, int n4) {
    int i = blockIdx.x * blockDim.x + threadIdx.x;
    if (i < n4) {
        float4 v = ((const float4*)x)[i];
        ushort4 o;
        o.x = f2bf(v.x); o.y = f2bf(v.y); o.z = f2bf(v.z); o.w = f2bf(v.w);
        ((ushort4*)y)[i] = o;
    }
}

// Pack Wcat (256 x NCOL: rows 0..127 = gcW, 128..255 = resW; fp32) into bf16 MFMA
// B-fragment order for K=256 GEMM:
// Wf[((kb*NT + nt)*64 + lane)*8 + j] = Wcat[kb*32 + (lane>>4)*8 + j][nt*16 + (lane&15)]
template <int NCOL>
__global__ void prep_wf2(const float* __restrict__ gcW, const float* __restrict__ resW,
                         unsigned short* __restrict__ Wf) {
    constexpr int NT = NCOL / 16;
    int tid = blockIdx.x * 256 + threadIdx.x;
    if (tid >= 256 * NCOL) return;
    int k = tid / NCOL, c = tid % NCOL;
    float v = (k < 128) ? gcW[k * NCOL + c] : resW[(k - 128) * NCOL + c];
    int kb = k >> 5, koff = k & 31, quad = koff >> 3, j = koff & 7;
    int nt = c >> 4, ncol = c & 15, lane = quad * 16 + ncol;
    Wf[((kb * NT + nt) * 64 + lane) * 8 + j] = f2bf(v);
}

// ---------------- fully-bucketed graph preprocessing ----------------

__global__ __launch_bounds__(256) void hist_kernel(
    const int* __restrict__ src, const int* __restrict__ dst, int ne, int D,
    int* __restrict__ dst_btot, int* __restrict__ src_btot) {
    __shared__ int hd[KBUCK], hs[KBUCK];
    const int t = threadIdx.x;
    const int tile0 = blockIdx.x * 4096;
    for (int i = t; i < KBUCK; i += 256) { hd[i] = 0; hs[i] = 0; }
    __syncthreads();
    #pragma unroll
    for (int j = 0; j < 16; j++) {
        int e = tile0 + j * 256 + t;
        if (e < ne) {
            atomicAdd(&hd[(unsigned)dst[e] / (unsigned)D], 1);
            atomicAdd(&hs[(unsigned)src[e] / (unsigned)D], 1);
        }
    }
    __syncthreads();
    for (int i = t; i < KBUCK; i += 256) {
        if (hd[i]) atomicAdd(&dst_btot[i], hd[i]);
        if (hs[i]) atomicAdd(&src_btot[i], hs[i]);
    }
}

__global__ __launch_bounds__(KBUCK) void scan_buckets(
    const int* __restrict__ dst_btot, const int* __restrict__ src_btot,
    int* __restrict__ dst_base, int* __restrict__ src_base,
    int* __restrict__ dst_cursor, int* __restrict__ src_cursor,
    int* __restrict__ row_ptr, int n, int ne) {
    __shared__ int t1[KBUCK], t2[KBUCK];
    const int t = threadIdx.x;
    int v1 = dst_btot[t], v2 = src_btot[t];
    t1[t] = v1; t2[t] = v2;
    for (int off = 1; off < KBUCK; off <<= 1) {
        __syncthreads();
        int a = (t >= off) ? t1[t - off] : 0;
        int b = (t >= off) ? t2[t - off] : 0;
        __syncthreads();
        t1[t] += a; t2[t] += b;
    }
    __syncthreads();
    int e1 = t1[t] - v1, e2 = t2[t] - v2;
    dst_base[t] = e1; src_base[t] = e2;
    dst_cursor[t] = e1; src_cursor[t] = e2;
    if (t == KBUCK - 1) {
        dst_base[KBUCK] = t1[t];
        src_base[KBUCK] = t2[t];
        row_ptr[n] = ne;
    }
}

// merged dst+src partition: one pass over (src,dst), writes both ebuf and sbuf.
__global__ __launch_bounds__(256) void partition_both(
    const int* __restrict__ src, const int* __restrict__ dst, int ne, int D,
    int* __restrict__ dst_cursor, int* __restrict__ src_cursor,
    uint2* __restrict__ ebuf, unsigned* __restrict__ sbuf) {
    __shared__ int hd[KBUCK], hs[KBUCK];
    __shared__ int gbd[KBUCK], gbs[KBUCK];
    const int t = threadIdx.x;
    const int tile0 = blockIdx.x * 4096;

    for (int i = t; i < KBUCK; i += 256) { hd[i] = 0; hs[i] = 0; }
    __syncthreads();

    int s[16], d[16], rd[16], rs[16];
    #pragma unroll
    for (int j = 0; j < 16; j++) {
        int e = tile0 + j * 256 + t;
        if (e < ne) {
            s[j] = src[e];
            d[j] = dst[e];
            rd[j] = atomicAdd(&hd[(unsigned)d[j] / (unsigned)D], 1);
            rs[j] = atomicAdd(&hs[(unsigned)s[j] / (unsigned)D], 1);
        }
    }
    __syncthreads();
    for (int i = t; i < KBUCK; i += 256) {
        int c1 = hd[i]; gbd[i] = c1 ? atomicAdd(&dst_cursor[i], c1) : 0;
        int c2 = hs[i]; gbs[i] = c2 ? atomicAdd(&src_cursor[i], c2) : 0;
    }
    __syncthreads();
    #pragma unroll
    for (int j = 0; j < 16; j++) {
        int e = tile0 + j * 256 + t;
        if (e < ne) {
            ebuf[gbd[(unsigned)d[j] / (unsigned)D] + rd[j]] = make_uint2((unsigned)s[j], (unsigned)d[j]);
            sbuf[gbs[(unsigned)s[j] / (unsigned)D] + rs[j]] = (unsigned)s[j];
        }
    }
}

// build_dst emits fused CSR entries {src, norm_s[src]} (uint2): one level of random
// indirection in spmm. norm_s built first (build_src launched before build_dst).
__global__ __launch_bounds__(256) void build_dst(
    const uint2* __restrict__ ebuf, const int* __restrict__ dst_base,
    const float* __restrict__ norm_s,
    int n, int D, int* __restrict__ row_ptr, float* __restrict__ norm_d,
    uint2* __restrict__ csr_e) {
    __shared__ int cnt[128], sc[128], rp[128], rank[128];
    const int b = blockIdx.x;
    const int d_lo = b * D;
    if (d_lo >= n) return;
    const int d_hi = (d_lo + D < n) ? d_lo + D : n;
    const int e0 = dst_base[b], e1 = dst_base[b + 1];
    const int t = threadIdx.x;

    if (t < 128) { cnt[t] = 0; rank[t] = 0; }
    __syncthreads();
    for (int i = e0 + t; i < e1; i += 256)
        atomicAdd(&cnt[(int)ebuf[i].y - d_lo], 1);
    __syncthreads();
    if (t < 128) sc[t] = cnt[t];
    __syncthreads();
    for (int off = 1; off < 128; off <<= 1) {
        int v = (t < 128 && t >= off) ? sc[t - off] : 0;
        __syncthreads();
        if (t < 128) sc[t] += v;
        __syncthreads();
    }
    if (t < 128) {
        rp[t] = e0 + sc[t] - cnt[t];   // exclusive
        int d = d_lo + t;
        if (d < d_hi) {
            row_ptr[d] = rp[t];
            norm_d[d] = rsqrtf(fmaxf((float)cnt[t], 1.0f));
        }
    }
    __syncthreads();
    for (int i = e0 + t; i < e1; i += 256) {
        uint2 ed = ebuf[i];
        int dd = (int)ed.y - d_lo;
        int r = atomicAdd(&rank[dd], 1);
        csr_e[rp[dd] + r] = make_uint2(ed.x, __float_as_uint(norm_s[(int)ed.x]));
    }
}

__global__ __launch_bounds__(256) void build_src(
    const unsigned* __restrict__ sbuf, const int* __restrict__ src_base,
    int n, int D, float* __restrict__ norm_s) {
    __shared__ int cnt[128];
    const int b = blockIdx.x;
    const int d_lo = b * D;
    if (d_lo >= n) return;
    const int d_hi = (d_lo + D < n) ? d_lo + D : n;
    const int e0 = src_base[b], e1 = src_base[b + 1];
    const int t = threadIdx.x;
    if (t < 128) cnt[t] = 0;
    __syncthreads();
    for (int i = e0 + t; i < e1; i += 256)
        atomicAdd(&cnt[(int)sbuf[i] - d_lo], 1);
    __syncthreads();
    if (t < 128 && d_lo + t < d_hi)
        norm_s[d_lo + t] = rsqrtf(fmaxf((float)cnt[t], 1.0f));
}

// ---------------- fused layer: spmm (round-3 gather) + MFMA GEMM ----------------
// Round-13: kill the U round-trip (51.2MB write + 51.2MB uncoalesced read per layer).
// Block = 4 waves x 16 nodes = 64 rows. Each wave aggregates its 16 nodes with the
// round-3 inner loop (SMEM entry loads, zero-row redirect, saddr gathers — the best
// measured spmm structure, 60.9us) into its PRIVATE 16x256 LDS slice, then loads its
// MFMA A-fragments from that slice (wave w's A-rows == wave w's nodes, so no cross-
// wave traffic) and runs the existing 64-MFMA GEMM with B straight from L2-resident
// Wf. LDS = 32KB -> 5 blocks/CU (~20 waves), same TLP regime as the split spmm.
// Activations ping-pong (in != out), so there is no read/write race.

template <int NCOL, bool RELU, bool OUT_BF16>
__global__ __launch_bounds__(256) void spmm_gemm(
    const unsigned short* __restrict__ X, const int* __restrict__ row_ptr,
    const uint2* __restrict__ csr_e, const float* __restrict__ norm_d,
    const unsigned short* __restrict__ Wf, const float* __restrict__ bias,
    void* __restrict__ outv, int n) {
    constexpr int NT = NCOL / 16;
    __shared__ unsigned short Us[64 * 256];   // 32 KB

    const int t = threadIdx.x;
    const int wave = t >> 6, lane = t & 63;
    const int base = blockIdx.x * 64 + wave * 16;   // this wave's 16 nodes
    unsigned short* Uw = Us + wave * (16 * 256);

    const unsigned voff = (unsigned)(lane << 2);   // byte offset within row
    const char* Xc = (const char*)X;

    // ---- phase 1: aggregate 16 nodes into the wave's LDS slice ----
    for (int ni = 0; ni < 16; ni++) {
        const int node = base + ni;
        unsigned short* Ur = Uw + ni * 256;
        if (node < n) {
            const int e0 = __builtin_amdgcn_readfirstlane(row_ptr[node]);
            const int e1 = __builtin_amdgcn_readfirstlane(row_ptr[node + 1]);
            const float ndv = norm_d[node];
            float ap0 = 0.f, ap1 = 0.f, as0 = 0.f, as1 = 0.f;

            for (int c = e0; c < e1; c += 16) {
                uint64_t E0, E1, E2, E3, E4, E5, E6, E7, E8, E9, Ea, Eb, Ec, Ed, Ee, Ef;
                {
                    uint64_t ep = (uint64_t)(const char*)(csr_e + c);
                    asm volatile(
                        "s_load_dwordx2 %[o0], %[a], 0x0\n\t"
                        "s_load_dwordx2 %[o1], %[a], 0x8\n\t"
                        "s_load_dwordx2 %[o2], %[a], 0x10\n\t"
                        "s_load_dwordx2 %[o3], %[a], 0x18\n\t"
                        "s_load_dwordx2 %[o4], %[a], 0x20\n\t"
                        "s_load_dwordx2 %[o5], %[a], 0x28\n\t"
                        "s_load_dwordx2 %[o6], %[a], 0x30\n\t"
                        "s_load_dwordx2 %[o7], %[a], 0x38\n\t"
                        "s_load_dwordx2 %[o8], %[a], 0x40\n\t"
                        "s_load_dwordx2 %[o9], %[a], 0x48\n\t"
                        "s_load_dwordx2 %[oa], %[a], 0x50\n\t"
                        "s_load_dwordx2 %[ob], %[a], 0x58\n\t"
                        "s_load_dwordx2 %[oc], %[a], 0x60\n\t"
                        "s_load_dwordx2 %[od], %[a], 0x68\n\t"
                        "s_load_dwordx2 %[oe], %[a], 0x70\n\t"
                        "s_load_dwordx2 %[of], %[a], 0x78\n\t"
                        "s_waitcnt lgkmcnt(0)"
                        : [o0] "=&s"(E0), [o1] "=&s"(E1), [o2] "=&s"(E2), [o3] "=&s"(E3),
                          [o4] "=&s"(E4), [o5] "=&s"(E5), [o6] "=&s"(E6), [o7] "=&s"(E7),
                          [o8] "=&s"(E8), [o9] "=&s"(E9), [oa] "=&s"(Ea), [ob] "=&s"(Eb),
                          [oc] "=&s"(Ec), [od] "=&s"(Ed), [oe] "=&s"(Ee), [of] "=&s"(Ef)
                        : [a] "s"(ep)
                        : "memory");
                }

                unsigned q[16];
                float wv[16];

#define PREP(i, Ei)                                                             \
                {                                                               \
                    int sv = (int)(unsigned)(Ei);                               \
                    unsigned wu = (unsigned)((Ei) >> 32);                       \
                    const bool val = (c + i) < e1;      /* wave-uniform */      \
                    sv = val ? sv : n;                  /* s_cselect */         \
                    wu = val ? wu : 0u;                 /* s_cselect */         \
                    wv[i] = u2f(wu);                                            \
                    unsigned off = (((unsigned)sv) << 8) + voff;                \
                    q[i] = *(const unsigned*)(Xc + off);                        \
                }
                PREP(0, E0)  PREP(1, E1)  PREP(2, E2)  PREP(3, E3)
                PREP(4, E4)  PREP(5, E5)  PREP(6, E6)  PREP(7, E7)
                PREP(8, E8)  PREP(9, E9)  PREP(10, Ea) PREP(11, Eb)
                PREP(12, Ec) PREP(13, Ed) PREP(14, Ee) PREP(15, Ef)
#undef PREP

                #pragma unroll
                for (int i = 0; i < 16; i++) {
                    unsigned qq = q[i];
                    float x0 = u2f(qq << 16);
                    float x1 = u2f(qq & 0xffff0000u);
                    ap0 += x0; ap1 += x1;
                    as0 = fmaf(wv[i], x0, as0);
                    as1 = fmaf(wv[i], x1, as1);
                }
            }

            ushort2 gc, rs;
            gc.x = f2bf(ndv * as0); gc.y = f2bf(ndv * as1);
            rs.x = f2bf(ap0);       rs.y = f2bf(ap1);
            *(ushort2*)(Ur + lane * 2) = gc;
            *(ushort2*)(Ur + 128 + lane * 2) = rs;
        } else {
            *(ushort2*)(Ur + lane * 2) = make_ushort2(0, 0);
            *(ushort2*)(Ur + 128 + lane * 2) = make_ushort2(0, 0);
        }
    }

    __syncthreads();   // LDS visibility (cross-lane within wave + uniform barrier)

    // ---- phase 2: GEMM for this wave's 16 rows (A from own LDS slice) ----
    const int am_l = lane & 15;
    const int kq = (lane >> 4) * 8;
    bf16x8 afrag[8];
    #pragma unroll
    for (int kb = 0; kb < 8; kb++)
        afrag[kb] = *(const bf16x8*)(Uw + am_l * 256 + kq + kb * 32);

    const int orow = base + (lane >> 4) * 4;
    const bf16x8* Wv = (const bf16x8*)Wf;

    #pragma unroll 1
    for (int nt = 0; nt < NT; nt++) {
        f32x4 acc = {0.f, 0.f, 0.f, 0.f};
        #pragma unroll
        for (int kb = 0; kb < 8; kb++) {
            bf16x8 b = Wv[(kb * NT + nt) * 64 + lane];
            acc = __builtin_amdgcn_mfma_f32_16x16x32_bf16(afrag[kb], b, acc, 0, 0, 0);
        }
        const int gcol = nt * 16 + (lane & 15);
        const float bv = bias[gcol];
        #pragma unroll
        for (int r = 0; r < 4; r++) {
            int gm = orow + r;
            if (gm < n) {
                float v = acc[r] + bv;
                if (RELU) v = fmaxf(v, 0.f);
                if constexpr (OUT_BF16)
                    ((unsigned short*)outv)[(size_t)gm * NCOL + gcol] = f2bf(v);
                else
                    ((float*)outv)[(size_t)gm * NCOL + gcol] = v;
            }
        }
    }
}

// ---------------- launch ----------------

extern "C" void kernel_launch(void* const* d_in, const int* in_sizes, int n_in,
                              void* d_out, int out_size, void* d_ws, size_t ws_size,
                              hipStream_t stream) {
    const float* raw_x  = (const float*)d_in[0];
    const int*   src    = (const int*)d_in[1];
    const int*   dst    = (const int*)d_in[2];
    const float* gc_w0  = (const float*)d_in[3];
    const float* gc_b0  = (const float*)d_in[4];
    const float* gc_w1  = (const float*)d_in[5];
    const float* gc_b1  = (const float*)d_in[6];
    const float* gc_w2  = (const float*)d_in[7];
    const float* gc_b2  = (const float*)d_in[8];
    const float* res_w0 = (const float*)d_in[9];
    const float* res_w1 = (const float*)d_in[10];
    const float* res_w2 = (const float*)d_in[11];

    const int n  = in_sizes[0] / NFEAT;   // 100000
    const int ne = in_sizes[1];           // 1600000
    float* out = (float*)d_out;
    const int D = (n + KBUCK - 1) / KBUCK;   // nodes per bucket (98, <=128)

    // workspace layout (activation buffers have an extra zeroed row n; csr_e has
    // 48 zeroed slack entries). U is gone — activations ping-pong Xb->X1b->X2b.
    char* w = (char*)d_ws;
    unsigned short* Xb  = (unsigned short*)w; w += (size_t)(n + 1) * 128 * sizeof(unsigned short); // 25.6 MB
    unsigned short* X1b = (unsigned short*)w; w += (size_t)(n + 1) * 128 * sizeof(unsigned short); // 25.6 MB
    unsigned short* X2b = (unsigned short*)w; w += (size_t)(n + 1) * 128 * sizeof(unsigned short); // 25.6 MB
    float* norm_s = (float*)w;   w += (size_t)n * sizeof(float);
    float* norm_d = (float*)w;   w += (size_t)n * sizeof(float);
    int* row_ptr = (int*)w;      w += (size_t)(n + 1) * sizeof(int);
    uint2* csr_e = (uint2*)w;    w += (size_t)(ne + 48) * sizeof(uint2);   // 12.8 MB {src, ns}
    uint2* ebuf = (uint2*)w;     w += (size_t)ne * sizeof(uint2);          // 12.8 MB
    unsigned* sbuf = (unsigned*)w; w += (size_t)ne * sizeof(unsigned);     // 6.4 MB
    int* dst_btot = (int*)w;     w += KBUCK * sizeof(int);
    int* src_btot = (int*)w;     w += KBUCK * sizeof(int);
    int* dst_base = (int*)w;     w += (KBUCK + 1) * sizeof(int);
    int* src_base = (int*)w;     w += (KBUCK + 1) * sizeof(int);
    int* dst_cursor = (int*)w;   w += KBUCK * sizeof(int);
    int* src_cursor = (int*)w;   w += KBUCK * sizeof(int);
    unsigned short* Wf0 = (unsigned short*)w; w += 256 * 128 * sizeof(unsigned short);
    unsigned short* Wf1 = (unsigned short*)w; w += 256 * 128 * sizeof(unsigned short);
    unsigned short* Wf2 = (unsigned short*)w; w += 256 * 64 * sizeof(unsigned short);

    const int tiles = (ne + 4095) / 4096;

    // --- preprocessing: bf16 cast, weight fragments, bucketed CSR + degrees ---
    cast_bf16_kernel<<<(n * (NFEAT / 4) + 255) / 256, 256, 0, stream>>>(raw_x, Xb, n * (NFEAT / 4));
    // zero row n of activation buffers (spmm pad-redirect target) + csr_e slack
    zero_ints<<<1, 64, 0, stream>>>((int*)(Xb + (size_t)n * 128), 64);
    zero_ints<<<1, 64, 0, stream>>>((int*)(X1b + (size_t)n * 128), 64);
    zero_ints<<<1, 64, 0, stream>>>((int*)(X2b + (size_t)n * 128), 64);
    zero_ints<<<1, 96, 0, stream>>>((int*)(csr_e + ne), 96);
    prep_wf2<128><<<128, 256, 0, stream>>>(gc_w0, res_w0, Wf0);
    prep_wf2<128><<<128, 256, 0, stream>>>(gc_w1, res_w1, Wf1);
    prep_wf2<64><<<64, 256, 0, stream>>>(gc_w2, res_w2, Wf2);
    zero_ints<<<(2 * KBUCK + 255) / 256, 256, 0, stream>>>(dst_btot, 2 * KBUCK); // dst_btot+src_btot contiguous
    hist_kernel<<<tiles, 256, 0, stream>>>(src, dst, ne, D, dst_btot, src_btot);
    scan_buckets<<<1, KBUCK, 0, stream>>>(dst_btot, src_btot, dst_base, src_base,
                                          dst_cursor, src_cursor, row_ptr, n, ne);
    partition_both<<<tiles, 256, 0, stream>>>(src, dst, ne, D, dst_cursor, src_cursor, ebuf, sbuf);
    build_src<<<KBUCK, 256, 0, stream>>>(sbuf, src_base, n, D, norm_s);
    build_dst<<<KBUCK, 256, 0, stream>>>(ebuf, dst_base, norm_s, n, D, row_ptr, norm_d, csr_e);

    const int fused_blocks = (n + 63) / 64;

    // --- layer 0: x1 = relu([nd*A(ns*x) | A x] @ [W0;R0] + b0) ---
    spmm_gemm<128, true, true><<<fused_blocks, 256, 0, stream>>>(
        Xb, row_ptr, csr_e, norm_d, Wf0, gc_b0, X1b, n);

    // --- layer 1 ---
    spmm_gemm<128, true, true><<<fused_blocks, 256, 0, stream>>>(
        X1b, row_ptr, csr_e, norm_d, Wf1, gc_b1, X2b, n);

    // --- layer 2: output 64-wide fp32, no relu ---
    spmm_gemm<64, false, false><<<fused_blocks, 256, 0, stream>>>(
        X2b, row_ptr, csr_e, norm_d, Wf2, gc_b2, out, n);
}